// Round 5
// baseline (292.065 us; speedup 1.0000x reference)
//
#include <hip/hip_runtime.h>
#include <math.h>

#define SIZE_N 100000
#define B_TOTAL 131072
#define D 128
#define K 64
#define NNEG 5
#define TILE 16
#define BLOCK 256
#define WPB 4
#define NTILES (B_TOTAL / TILE)        // 8192
#define GRID (NTILES / WPB)            // 2048
#define CWS 136                        // fallback LDS stride

#define CONV_BLOCKS 6250               // SIZE_N*D / 8 / BLOCK
#define GEMM_TILES 6250                // SIZE_N / 16
#define GEMM_BLOCKS ((GEMM_TILES + WPB - 1) / WPB)   // 1563

typedef short bf16x8 __attribute__((ext_vector_type(8)));
typedef float f32x4 __attribute__((ext_vector_type(4)));

union FragU { unsigned u[4]; bf16x8 v; };

// round-to-nearest-even fp32 -> bf16 (upper 16 bits)
__device__ __forceinline__ unsigned rne_hi(float x) {
    unsigned u = __float_as_uint(x);
    return (u + 0x7fffu + ((u >> 16) & 1u)) & 0xffff0000u;
}
__device__ __forceinline__ unsigned pkbf(float lo, float hi) {
    return (rne_hi(lo) >> 16) | rne_hi(hi);
}

__device__ __forceinline__ float log_sigmoid(float x) {
    return fminf(x, 0.f) - __logf(1.f + __expf(-fabsf(x)));
}

__global__ void zero_loss(float* out) { if (threadIdx.x == 0) out[0] = 0.f; }

// ---------------- fused pre-pass ----------------
// blocks [0, GEMM_BLOCKS): pre = ctx_emb @ comm_w.T -> bf16 [SIZE_N][K]  (launched first: longer tail)
// blocks [GEMM_BLOCKS, GEMM_BLOCKS+CONV_BLOCKS): node_emb fp32->bf16 (+ comm_w convert + loss zero)
__global__ __launch_bounds__(BLOCK) void prep_pass(
    const float* __restrict__ node, const float* __restrict__ ctx,
    const float* __restrict__ cw,
    short* __restrict__ nodeb, short* __restrict__ cwb, short* __restrict__ preb,
    float* __restrict__ out)
{
    __shared__ __align__(16) short ps[WPB][16][72];
    const int tid = threadIdx.x;

    if (blockIdx.x >= GEMM_BLOCKS) {
        const int cb = blockIdx.x - GEMM_BLOCKS;
        const size_t i = ((size_t)cb * BLOCK + tid) * 8;
        float4 v0 = *(const float4*)(node + i), v1 = *(const float4*)(node + i + 4);
        FragU f;
        f.u[0] = pkbf(v0.x, v0.y); f.u[1] = pkbf(v0.z, v0.w);
        f.u[2] = pkbf(v1.x, v1.y); f.u[3] = pkbf(v1.z, v1.w);
        *(bf16x8*)(nodeb + i) = f.v;
        if (cb == 0) {
            if (tid == 0) out[0] = 0.f;
#pragma unroll
            for (int t = 0; t < 4; ++t) {
                const int j = (tid * 4 + t) * 8;   // covers K*D = 8192
                float4 a = *(const float4*)(cw + j), b = *(const float4*)(cw + j + 4);
                FragU fc;
                fc.u[0] = pkbf(a.x, a.y); fc.u[1] = pkbf(a.z, a.w);
                fc.u[2] = pkbf(b.x, b.y); fc.u[3] = pkbf(b.z, b.w);
                *(bf16x8*)(cwb + j) = fc.v;
            }
        }
        return;
    }

    // ---- ctx @ comm_w.T GEMM branch (reads f32 inputs directly) ----
    const int lane = tid & 63, wid = tid >> 6;
    const int i15 = lane & 15, g = lane >> 4;
    const int tile = blockIdx.x * WPB + wid;
    if (tile >= GEMM_TILES) return;

    bf16x8 bfr[4][4];
#pragma unroll
    for (int ks = 0; ks < 4; ++ks)
#pragma unroll
        for (int nb = 0; nb < 4; ++nb) {
            const float* p = cw + (nb * 16 + i15) * D + ks * 32 + g * 8;
            float4 a = *(const float4*)p, b = *(const float4*)(p + 4);
            FragU f;
            f.u[0] = pkbf(a.x, a.y); f.u[1] = pkbf(a.z, a.w);
            f.u[2] = pkbf(b.x, b.y); f.u[3] = pkbf(b.z, b.w);
            bfr[ks][nb] = f.v;
        }

    const float* rp = ctx + (size_t)(tile * 16 + i15) * D + g * 8;
    const f32x4 z4 = {0.f, 0.f, 0.f, 0.f};
    f32x4 Ca[4] = {z4, z4, z4, z4};
#pragma unroll
    for (int ks = 0; ks < 4; ++ks) {
        float4 a = *(const float4*)(rp + ks * 32), b = *(const float4*)(rp + ks * 32 + 4);
        FragU f;
        f.u[0] = pkbf(a.x, a.y); f.u[1] = pkbf(a.z, a.w);
        f.u[2] = pkbf(b.x, b.y); f.u[3] = pkbf(b.z, b.w);
#pragma unroll
        for (int nb = 0; nb < 4; ++nb)
            Ca[nb] = __builtin_amdgcn_mfma_f32_16x16x32_bf16(f.v, bfr[ks][nb], Ca[nb], 0, 0, 0);
    }
    // LDS repack -> 16B-aligned full-line stores (was 2-byte scatter).
#pragma unroll
    for (int nb = 0; nb < 4; ++nb)
#pragma unroll
        for (int r = 0; r < 4; ++r)
            ps[wid][4 * g + r][nb * 16 + i15] = (short)(rne_hi(Ca[nb][r]) >> 16);
    asm volatile("s_waitcnt lgkmcnt(0)" ::: "memory");
    {
        const int ro = lane >> 2, co = (lane & 3) * 16;
        bf16x8 v0 = *(const bf16x8*)&ps[wid][ro][co];
        bf16x8 v1 = *(const bf16x8*)&ps[wid][ro][co + 8];
        short* dst = preb + (size_t)(tile * 16 + ro) * K + co;   // 16B-aligned (preb offset % 16 == 0)
        *(bf16x8*)dst = v0;
        *(bf16x8*)(dst + 8) = v1;
    }
}

// ---------------- main kernel: Q/P GEMM + precomputed-projection loss dots ----------------
__global__ __launch_bounds__(BLOCK, 2) void gcn_mfma_bf16(
    const int* __restrict__ w, const int* __restrict__ c, const int* __restrict__ neg,
    const short* __restrict__ nodeb, const short* __restrict__ preb,
    const short* __restrict__ cwb, float* __restrict__ out)
{
    __shared__ __align__(16) float qt[WPB][16][68];   // wave-private q transpose buffer

    const int tid = threadIdx.x;
    const int lane = tid & 63;
    const int wid = tid >> 6;
    const int i15 = lane & 15;
    const int g = lane >> 4;

    const int tile = blockIdx.x * WPB + wid;
    const int b0 = tile * TILE;
    const int bm = b0 + i15;

    // (1) index loads — first in issue order
    const int iw = w[bm];
    const int ic = c[bm];
    int ing[NNEG];
#pragma unroll
    for (int j = 0; j < NNEG; ++j) ing[j] = neg[bm * NNEG + j];

    // (0) LLC warm: stream the whole workspace (nodeb..preb..cwb contiguous, 38.4 MB) through
    //     the cache hierarchy with linear reads. Theory: stores from prep_pass do not allocate
    //     in the memory-side cache, so without this every gather below is an HBM-latency miss
    //     (FETCH_SIZE 76 MB ≈ tables re-fetched). 5×16B per thread; kept live per rule #17.
    uint4 wa0, wa1, wa2, wa3, wa4;
    {
        const uint4* wsv = (const uint4*)nodeb;
        const size_t NV = ((size_t)SIZE_N * D + (size_t)SIZE_N * K + (size_t)K * D) / 8; // 2,401,024
        const size_t stp = (size_t)GRID * BLOCK;                                         // 524,288
        const size_t p0 = (size_t)blockIdx.x * BLOCK + tid;
        wa0 = wsv[p0];
        wa1 = wsv[p0 + stp];
        wa2 = wsv[p0 + 2 * stp];
        wa3 = wsv[p0 + 3 * stp];
        wa4 = (p0 + 4 * stp < NV) ? wsv[p0 + 4 * stp] : wa0;
    }

    // (2) comm_w fragments straight from global (16 KB -> L1-resident)
    bf16x8 bfr[4][4];
#pragma unroll
    for (int ks = 0; ks < 4; ++ks)
#pragma unroll
        for (int nb = 0; nb < 4; ++nb)
            bfr[ks][nb] = *(const bf16x8*)&cwb[(nb * 16 + i15) * D + ks * 32 + g * 8];

    // (3) node row gathers (needed first, for Q/P GEMM)
    const short* wp = nodeb + (size_t)iw * D + g * 8;
    const short* cp = nodeb + (size_t)ic * D + g * 8;
    FragU wf[4], cf[4];
#pragma unroll
    for (int ks = 0; ks < 4; ++ks) {
        wf[ks].v = *(const bf16x8*)(wp + ks * 32);
        cf[ks].v = *(const bf16x8*)(cp + ks * 32);
    }

    // (4) ALL projection-row gathers issue upfront (128 B/row, A-frag layout: row=i15, k=g*8+e)
    bf16x8 pr0[1 + NNEG], pr1[1 + NNEG];
    {
        const short* p = preb + (size_t)ic * K + g * 8;
        pr0[0] = *(const bf16x8*)p;
        pr1[0] = *(const bf16x8*)(p + 32);
    }
#pragma unroll
    for (int j = 0; j < NNEG; ++j) {
        const short* p = preb + (size_t)ing[j] * K + g * 8;
        pr0[j + 1] = *(const bf16x8*)p;
        pr1[j + 1] = *(const bf16x8*)(p + 32);
    }

    // consume the warm loads (after all gathers have issued, so the vmcnt wait for these
    // oldest-in-flight loads does not drain the gather queue)
    asm volatile("" :: "v"(wa0.x), "v"(wa0.y), "v"(wa0.z), "v"(wa0.w),
                       "v"(wa1.x), "v"(wa1.y), "v"(wa1.z), "v"(wa1.w),
                       "v"(wa2.x), "v"(wa2.y), "v"(wa2.z), "v"(wa2.w),
                       "v"(wa3.x), "v"(wa3.y), "v"(wa3.z), "v"(wa3.w),
                       "v"(wa4.x), "v"(wa4.y), "v"(wa4.z), "v"(wa4.w));

    // (5) Q/P GEMMs
    const f32x4 z4 = {0.f, 0.f, 0.f, 0.f};
    f32x4 Qa[4] = {z4, z4, z4, z4};
    f32x4 Pa[4] = {z4, z4, z4, z4};
#pragma unroll
    for (int ks = 0; ks < 4; ++ks) {
        FragU pf;
#pragma unroll
        for (int t = 0; t < 4; ++t) {
            float al = __uint_as_float(wf[ks].u[t] << 16);
            float ah = __uint_as_float(wf[ks].u[t] & 0xffff0000u);
            float bl = __uint_as_float(cf[ks].u[t] << 16);
            float bh = __uint_as_float(cf[ks].u[t] & 0xffff0000u);
            pf.u[t] = pkbf(al * bl, ah * bh);
        }
#pragma unroll
        for (int nb = 0; nb < 4; ++nb) {
            Pa[nb] = __builtin_amdgcn_mfma_f32_16x16x32_bf16(wf[ks].v, bfr[ks][nb], Pa[nb], 0, 0, 0);
            Qa[nb] = __builtin_amdgcn_mfma_f32_16x16x32_bf16(pf.v, bfr[ks][nb], Qa[nb], 0, 0, 0);
        }
    }

    // (6) transpose q into bf16 B-frag layout via wave-private LDS
    //     write: q[pair=4g+r][col=16nb+i15];  read: q[pair=i15][k=g*8+e] (+32)
#pragma unroll
    for (int nb = 0; nb < 4; ++nb)
#pragma unroll
        for (int r = 0; r < 4; ++r)
            qt[wid][4 * g + r][nb * 16 + i15] = Qa[nb][r];
    asm volatile("s_waitcnt lgkmcnt(0)" ::: "memory");
    FragU q0, q1;
    {
        const float* rowp = &qt[wid][i15][0];
        float4 a = *(const float4*)(rowp + g * 8);
        float4 b = *(const float4*)(rowp + g * 8 + 4);
        q0.u[0] = pkbf(a.x, a.y); q0.u[1] = pkbf(a.z, a.w);
        q0.u[2] = pkbf(b.x, b.y); q0.u[3] = pkbf(b.z, b.w);
        float4 e = *(const float4*)(rowp + 32 + g * 8);
        float4 h = *(const float4*)(rowp + 32 + g * 8 + 4);
        q1.u[0] = pkbf(e.x, e.y); q1.u[1] = pkbf(e.z, e.w);
        q1.u[2] = pkbf(h.x, h.y); q1.u[3] = pkbf(h.z, h.w);
    }

    // (7) loss dots: C = pre_rows · q^T, take the diagonal (pair i15 lives at lane g=i15>>2)
    const int rstar = i15 - 4 * g;
    const bool valid = ((unsigned)rstar) < 4u;
    float lossAcc = 0.f;
#pragma unroll
    for (int j = 0; j < 1 + NNEG; ++j) {
        f32x4 Sa = z4;
        Sa = __builtin_amdgcn_mfma_f32_16x16x32_bf16(pr0[j], q0.v, Sa, 0, 0, 0);
        Sa = __builtin_amdgcn_mfma_f32_16x16x32_bf16(pr1[j], q1.v, Sa, 0, 0, 0);
        float s = (rstar == 0) ? Sa[0] : (rstar == 1) ? Sa[1] : (rstar == 2) ? Sa[2] : Sa[3];
        lossAcc += valid ? log_sigmoid(j == 0 ? s : -s) : 0.f;
    }

    // (8) epilogue: softmax(q), prior — R4-proven addressing, cached stores
    float* __restrict__ outq = out + 1;
    float* __restrict__ outp = out + 1 + (size_t)B_TOTAL * K;
#pragma unroll
    for (int r = 0; r < 4; ++r) {
        const size_t obase = (size_t)(b0 + g * 4 + r) * K + i15;
        {
            float m = fmaxf(fmaxf(Qa[0][r], Qa[1][r]), fmaxf(Qa[2][r], Qa[3][r]));
            m = fmaxf(m, __shfl_xor(m, 1, 64)); m = fmaxf(m, __shfl_xor(m, 2, 64));
            m = fmaxf(m, __shfl_xor(m, 4, 64)); m = fmaxf(m, __shfl_xor(m, 8, 64));
            float e0 = __expf(Qa[0][r] - m), e1 = __expf(Qa[1][r] - m);
            float e2 = __expf(Qa[2][r] - m), e3 = __expf(Qa[3][r] - m);
            float s = e0 + e1 + e2 + e3;
            s += __shfl_xor(s, 1, 64); s += __shfl_xor(s, 2, 64);
            s += __shfl_xor(s, 4, 64); s += __shfl_xor(s, 8, 64);
            float inv = 1.f / s;
            outq[obase]      = e0 * inv;
            outq[obase + 16] = e1 * inv;
            outq[obase + 32] = e2 * inv;
            outq[obase + 48] = e3 * inv;
        }
        {
            float m = fmaxf(fmaxf(Pa[0][r], Pa[1][r]), fmaxf(Pa[2][r], Pa[3][r]));
            m = fmaxf(m, __shfl_xor(m, 1, 64)); m = fmaxf(m, __shfl_xor(m, 2, 64));
            m = fmaxf(m, __shfl_xor(m, 4, 64)); m = fmaxf(m, __shfl_xor(m, 8, 64));
            float e0 = __expf(Pa[0][r] - m), e1 = __expf(Pa[1][r] - m);
            float e2 = __expf(Pa[2][r] - m), e3 = __expf(Pa[3][r] - m);
            float s = e0 + e1 + e2 + e3;
            s += __shfl_xor(s, 1, 64); s += __shfl_xor(s, 2, 64);
            s += __shfl_xor(s, 4, 64); s += __shfl_xor(s, 8, 64);
            float inv = 1.f / s;
            outp[obase]      = e0 * inv;
            outp[obase + 16] = e1 * inv;
            outp[obase + 32] = e2 * inv;
            outp[obase + 48] = e3 * inv;
        }
    }

    // each pair counted exactly once per j
    float tot = lossAcc;
#pragma unroll
    for (int msk = 1; msk < 64; msk <<= 1) tot += __shfl_xor(tot, msk, 64);
    if (lane == 0) atomicAdd(out, -tot / (float)B_TOTAL);
}

// ---------------- fp32 fallback (R2 kernel, proven) ----------------
__global__ __launch_bounds__(BLOCK) void gcn_mfma_kernel(
    const int* __restrict__ w, const int* __restrict__ c, const int* __restrict__ neg,
    const float* __restrict__ node_emb, const float* __restrict__ ctx_emb,
    const float* __restrict__ comm_w, float* __restrict__ out)
{
    __shared__ __align__(16) short cw_lds[K * CWS];
    const int tid = threadIdx.x;
    const int lane = tid & 63;
    const int wid = tid >> 6;
    const int i15 = lane & 15;
    const int g = lane >> 4;

    for (int i = tid * 4; i < K * D; i += BLOCK * 4) {
        float4 v = *(const float4*)(comm_w + i);
        int row = i >> 7, col = i & 127;
        unsigned* dst = (unsigned*)&cw_lds[row * CWS + col];
        dst[0] = pkbf(v.x, v.y);
        dst[1] = pkbf(v.z, v.w);
    }
    __syncthreads();

    bf16x8 bfr[4][4];
#pragma unroll
    for (int ks = 0; ks < 4; ++ks)
#pragma unroll
        for (int nb = 0; nb < 4; ++nb)
            bfr[ks][nb] = *(const bf16x8*)&cw_lds[(nb * 16 + i15) * CWS + ks * 32 + g * 8];

    const int tile = blockIdx.x * WPB + wid;
    const int b0 = tile * TILE;
    const int bm = b0 + i15;
    const int iw = w[bm], ic = c[bm];
    int ing[NNEG];
#pragma unroll
    for (int j = 0; j < NNEG; ++j) ing[j] = neg[bm * NNEG + j];

    const f32x4 z4 = {0.f, 0.f, 0.f, 0.f};
    f32x4 Qa[4] = {z4, z4, z4, z4};
    f32x4 Pa[4] = {z4, z4, z4, z4};

#pragma unroll
    for (int ks = 0; ks < 4; ++ks) {
        const float* wp = node_emb + (size_t)iw * D + ks * 32 + g * 8;
        const float* cp = node_emb + (size_t)ic * D + ks * 32 + g * 8;
        float4 w0 = *(const float4*)wp, w1 = *(const float4*)(wp + 4);
        float4 c0 = *(const float4*)cp, c1 = *(const float4*)(cp + 4);
        FragU wf, pf;
        wf.u[0] = pkbf(w0.x, w0.y);               wf.u[1] = pkbf(w0.z, w0.w);
        wf.u[2] = pkbf(w1.x, w1.y);               wf.u[3] = pkbf(w1.z, w1.w);
        pf.u[0] = pkbf(w0.x * c0.x, w0.y * c0.y); pf.u[1] = pkbf(w0.z * c0.z, w0.w * c0.w);
        pf.u[2] = pkbf(w1.x * c1.x, w1.y * c1.y); pf.u[3] = pkbf(w1.z * c1.z, w1.w * c1.w);
#pragma unroll
        for (int nb = 0; nb < 4; ++nb) {
            Pa[nb] = __builtin_amdgcn_mfma_f32_16x16x32_bf16(wf.v, bfr[ks][nb], Pa[nb], 0, 0, 0);
            Qa[nb] = __builtin_amdgcn_mfma_f32_16x16x32_bf16(pf.v, bfr[ks][nb], Qa[nb], 0, 0, 0);
        }
    }

    float lossAcc = 0.f;
#pragma unroll
    for (int j = 0; j < 1 + NNEG; ++j) {
        const int idx = (j == 0) ? ic : ing[j - 1];
        const float* ebase = ctx_emb + (size_t)idx * D;
        f32x4 Fa[4] = {z4, z4, z4, z4};
#pragma unroll
        for (int ks = 0; ks < 4; ++ks) {
            const float* ep = ebase + ks * 32 + g * 8;
            float4 e0 = *(const float4*)ep, e1 = *(const float4*)(ep + 4);
            FragU ef;
            ef.u[0] = pkbf(e0.x, e0.y); ef.u[1] = pkbf(e0.z, e0.w);
            ef.u[2] = pkbf(e1.x, e1.y); ef.u[3] = pkbf(e1.z, e1.w);
#pragma unroll
            for (int nb = 0; nb < 4; ++nb)
                Fa[nb] = __builtin_amdgcn_mfma_f32_16x16x32_bf16(ef.v, bfr[ks][nb], Fa[nb], 0, 0, 0);
        }
#pragma unroll
        for (int r = 0; r < 4; ++r) {
            float s = Fa[0][r] * Qa[0][r] + Fa[1][r] * Qa[1][r] + Fa[2][r] * Qa[2][r] + Fa[3][r] * Qa[3][r];
            s += __shfl_xor(s, 1, 64);
            s += __shfl_xor(s, 2, 64);
            s += __shfl_xor(s, 4, 64);
            s += __shfl_xor(s, 8, 64);
            lossAcc += log_sigmoid(j == 0 ? s : -s);
        }
    }

    float* __restrict__ outq = out + 1;
    float* __restrict__ outp = out + 1 + (size_t)B_TOTAL * K;
#pragma unroll
    for (int r = 0; r < 4; ++r) {
        const size_t obase = (size_t)(b0 + g * 4 + r) * K + i15;
        {
            float m = fmaxf(fmaxf(Qa[0][r], Qa[1][r]), fmaxf(Qa[2][r], Qa[3][r]));
            m = fmaxf(m, __shfl_xor(m, 1, 64)); m = fmaxf(m, __shfl_xor(m, 2, 64));
            m = fmaxf(m, __shfl_xor(m, 4, 64)); m = fmaxf(m, __shfl_xor(m, 8, 64));
            float e0 = __expf(Qa[0][r] - m), e1 = __expf(Qa[1][r] - m);
            float e2 = __expf(Qa[2][r] - m), e3 = __expf(Qa[3][r] - m);
            float s = e0 + e1 + e2 + e3;
            s += __shfl_xor(s, 1, 64); s += __shfl_xor(s, 2, 64);
            s += __shfl_xor(s, 4, 64); s += __shfl_xor(s, 8, 64);
            float inv = 1.f / s;
            outq[obase]      = e0 * inv; outq[obase + 16] = e1 * inv;
            outq[obase + 32] = e2 * inv; outq[obase + 48] = e3 * inv;
        }
        {
            float m = fmaxf(fmaxf(Pa[0][r], Pa[1][r]), fmaxf(Pa[2][r], Pa[3][r]));
            m = fmaxf(m, __shfl_xor(m, 1, 64)); m = fmaxf(m, __shfl_xor(m, 2, 64));
            m = fmaxf(m, __shfl_xor(m, 4, 64)); m = fmaxf(m, __shfl_xor(m, 8, 64));
            float e0 = __expf(Pa[0][r] - m), e1 = __expf(Pa[1][r] - m);
            float e2 = __expf(Pa[2][r] - m), e3 = __expf(Pa[3][r] - m);
            float s = e0 + e1 + e2 + e3;
            s += __shfl_xor(s, 1, 64); s += __shfl_xor(s, 2, 64);
            s += __shfl_xor(s, 4, 64); s += __shfl_xor(s, 8, 64);
            float inv = 1.f / s;
            outp[obase]      = e0 * inv; outp[obase + 16] = e1 * inv;
            outp[obase + 32] = e2 * inv; outp[obase + 48] = e3 * inv;
        }
    }

    float tot = lossAcc;
#pragma unroll
    for (int msk = 1; msk < 64; msk <<= 1) tot += __shfl_xor(tot, msk, 64);
    if (lane == 0) atomicAdd(out, -tot / (16.f * (float)B_TOTAL));
}

extern "C" void kernel_launch(void* const* d_in, const int* in_sizes, int n_in,
                              void* d_out, int out_size, void* d_ws, size_t ws_size,
                              hipStream_t stream) {
    const int* w = (const int*)d_in[0];
    const int* c = (const int*)d_in[1];
    const int* neg = (const int*)d_in[2];
    // d_in[3] = temp (unused)
    const float* node_emb = (const float*)d_in[4];
    const float* ctx_emb = (const float*)d_in[5];
    const float* comm_w = (const float*)d_in[6];
    float* out = (float*)d_out;

    const size_t tbl_elems = (size_t)SIZE_N * D;
    const size_t pre_elems = (size_t)SIZE_N * K;
    const size_t need = (tbl_elems + pre_elems + (size_t)K * D) * sizeof(short); // ~38.4 MB

    if (ws_size >= need) {
        short* nodeb = (short*)d_ws;
        short* preb = nodeb + tbl_elems;
        short* cwb = preb + pre_elems;
        prep_pass<<<CONV_BLOCKS + GEMM_BLOCKS, BLOCK, 0, stream>>>(
            node_emb, ctx_emb, comm_w, nodeb, cwb, preb, out);
        gcn_mfma_bf16<<<GRID, BLOCK, 0, stream>>>(w, c, neg, nodeb, preb, cwb, out);
    } else {
        zero_loss<<<1, 64, 0, stream>>>(out);
        gcn_mfma_kernel<<<GRID, BLOCK, 0, stream>>>(w, c, neg, node_emb, ctx_emb, comm_w, out);
    }
}

// Round 6
// 289.819 us; speedup vs baseline: 1.0078x; 1.0078x over previous
//
#include <hip/hip_runtime.h>
#include <math.h>

#define SIZE_N 100000
#define B_TOTAL 131072
#define D 128
#define K 64
#define NNEG 5
#define TILE 16
#define BLOCK 256
#define WPB 4
#define NTILES (B_TOTAL / TILE)        // 8192
#define GRID (NTILES / WPB)            // 2048
#define CWS 136                        // fallback LDS stride

#define CONV_BLOCKS 6250               // SIZE_N*D / 8 / BLOCK
#define GEMM_TILES 6250                // SIZE_N / 16
#define GEMM_BLOCKS ((GEMM_TILES + WPB - 1) / WPB)   // 1563

typedef short bf16x8 __attribute__((ext_vector_type(8)));
typedef float f32x4 __attribute__((ext_vector_type(4)));

union FragU { unsigned u[4]; bf16x8 v; };

// round-to-nearest-even fp32 -> bf16 (upper 16 bits)
__device__ __forceinline__ unsigned rne_hi(float x) {
    unsigned u = __float_as_uint(x);
    return (u + 0x7fffu + ((u >> 16) & 1u)) & 0xffff0000u;
}
__device__ __forceinline__ unsigned pkbf(float lo, float hi) {
    return (rne_hi(lo) >> 16) | rne_hi(hi);
}

// f32 -> fp8 e4m3fn, RNE, flush-to-zero below 2^-6, clamp at 448
__device__ __forceinline__ unsigned char f32_fp8(float x) {
    unsigned u = __float_as_uint(x);
    unsigned s = (u >> 24) & 0x80u;
    int e = (int)((u >> 23) & 0xffu);
    unsigned m = u & 0x7fffffu;
    if (e < 121) return (unsigned char)s;               // |x| < 2^-6 -> signed zero
    unsigned n = (((unsigned)(e - 120)) << 23) | m;     // exp at bit23, mant3 at bits 20..22
    n = (n + 0x7ffffu + ((n >> 20) & 1u)) >> 20;        // RNE, carry propagates into exp
    if (n > 0x7Eu) n = 0x7Eu;                           // clamp to 448 (0x7F = NaN)
    return (unsigned char)(s | n);
}

// two packed fp8 e4m3 bytes -> packed bf16x2 (subnormals -> 0)
__device__ __forceinline__ unsigned fp8pair_bf16(unsigned two) {
    unsigned t0 = two & 0xffu, t1 = (two >> 8) & 0xffu;
    unsigned lo = (t0 & 0x78u) ? (((t0 & 0x80u) << 8) | (((t0 & 0x7fu) + 960u) << 4)) : 0u;
    unsigned hi = (t1 & 0x78u) ? (((t1 & 0x80u) << 8) | (((t1 & 0x7fu) + 960u) << 4)) : 0u;
    return lo | (hi << 16);
}

__device__ __forceinline__ float log_sigmoid(float x) {
    return fminf(x, 0.f) - __logf(1.f + __expf(-fabsf(x)));
}

__global__ void zero_loss(float* out) { if (threadIdx.x == 0) out[0] = 0.f; }

// ---------------- fused pre-pass ----------------
// blocks [0, GEMM_BLOCKS): pre = ctx_emb @ comm_w.T -> fp8 e4m3 [SIZE_N][K], A-frag-permuted rows
// blocks [GEMM_BLOCKS, ...): node_emb fp32->bf16 (+ comm_w convert + loss zero)
__global__ __launch_bounds__(BLOCK) void prep_pass(
    const float* __restrict__ node, const float* __restrict__ ctx,
    const float* __restrict__ cw,
    short* __restrict__ nodeb, short* __restrict__ cwb, unsigned char* __restrict__ preb,
    float* __restrict__ out)
{
    __shared__ __align__(16) unsigned char ps8[WPB][16][64];
    const int tid = threadIdx.x;

    if (blockIdx.x >= GEMM_BLOCKS) {
        const int cb = blockIdx.x - GEMM_BLOCKS;
        const size_t i = ((size_t)cb * BLOCK + tid) * 8;
        float4 v0 = *(const float4*)(node + i), v1 = *(const float4*)(node + i + 4);
        FragU f;
        f.u[0] = pkbf(v0.x, v0.y); f.u[1] = pkbf(v0.z, v0.w);
        f.u[2] = pkbf(v1.x, v1.y); f.u[3] = pkbf(v1.z, v1.w);
        *(bf16x8*)(nodeb + i) = f.v;
        if (cb == 0) {
            if (tid == 0) out[0] = 0.f;
#pragma unroll
            for (int t = 0; t < 4; ++t) {
                const int j = (tid * 4 + t) * 8;   // covers K*D = 8192
                float4 a = *(const float4*)(cw + j), b = *(const float4*)(cw + j + 4);
                FragU fc;
                fc.u[0] = pkbf(a.x, a.y); fc.u[1] = pkbf(a.z, a.w);
                fc.u[2] = pkbf(b.x, b.y); fc.u[3] = pkbf(b.z, b.w);
                *(bf16x8*)(cwb + j) = fc.v;
            }
        }
        return;
    }

    // ---- ctx @ comm_w.T GEMM branch (reads f32 inputs directly) ----
    const int lane = tid & 63, wid = tid >> 6;
    const int i15 = lane & 15, g = lane >> 4;
    const int tile = blockIdx.x * WPB + wid;
    if (tile >= GEMM_TILES) return;

    bf16x8 bfr[4][4];
#pragma unroll
    for (int ks = 0; ks < 4; ++ks)
#pragma unroll
        for (int nb = 0; nb < 4; ++nb) {
            const float* p = cw + (nb * 16 + i15) * D + ks * 32 + g * 8;
            float4 a = *(const float4*)p, b = *(const float4*)(p + 4);
            FragU f;
            f.u[0] = pkbf(a.x, a.y); f.u[1] = pkbf(a.z, a.w);
            f.u[2] = pkbf(b.x, b.y); f.u[3] = pkbf(b.z, b.w);
            bfr[ks][nb] = f.v;
        }

    const float* rp = ctx + (size_t)(tile * 16 + i15) * D + g * 8;
    const f32x4 z4 = {0.f, 0.f, 0.f, 0.f};
    f32x4 Ca[4] = {z4, z4, z4, z4};
#pragma unroll
    for (int ks = 0; ks < 4; ++ks) {
        float4 a = *(const float4*)(rp + ks * 32), b = *(const float4*)(rp + ks * 32 + 4);
        FragU f;
        f.u[0] = pkbf(a.x, a.y); f.u[1] = pkbf(a.z, a.w);
        f.u[2] = pkbf(b.x, b.y); f.u[3] = pkbf(b.z, b.w);
#pragma unroll
        for (int nb = 0; nb < 4; ++nb)
            Ca[nb] = __builtin_amdgcn_mfma_f32_16x16x32_bf16(f.v, bfr[ks][nb], Ca[nb], 0, 0, 0);
    }
    // fp8 encode + A-frag permutation via LDS, then coalesced 16B row stores.
    // Permuted byte position p(k): k<32 -> (k>>3)*16 + (k&7); else ((k-32)>>3)*16 + 8 + ((k-32)&7)
    // so the main kernel's lane-g 16B load covers both K-halves of its fragment.
#pragma unroll
    for (int nb = 0; nb < 4; ++nb) {
        const int k0 = nb * 16 + i15;
        const int pcol = (nb < 2) ? ((k0 >> 3) * 16 + (k0 & 7))
                                  : (((k0 - 32) >> 3) * 16 + 8 + ((k0 - 32) & 7));
#pragma unroll
        for (int r = 0; r < 4; ++r)
            ps8[wid][4 * g + r][pcol] = f32_fp8(Ca[nb][r]);
    }
    asm volatile("s_waitcnt lgkmcnt(0)" ::: "memory");
    {
        const int ro = lane >> 2, qd = lane & 3;
        uint4 vv = *(const uint4*)&ps8[wid][ro][qd * 16];
        *(uint4*)(preb + ((size_t)(tile * 16 + ro)) * 64 + qd * 16) = vv;  // 16B aligned, 1KB/wave
    }
}

// ---------------- main kernel: Q/P GEMM + fp8-projection loss dots ----------------
__global__ __launch_bounds__(BLOCK, 2) void gcn_mfma_bf16(
    const int* __restrict__ w, const int* __restrict__ c, const int* __restrict__ neg,
    const short* __restrict__ nodeb, const unsigned char* __restrict__ preb,
    const short* __restrict__ cwb, float* __restrict__ out)
{
    __shared__ __align__(16) float qt[WPB][16][68];   // wave-private transpose/repack buffer

    const int tid = threadIdx.x;
    const int lane = tid & 63;
    const int wid = tid >> 6;
    const int i15 = lane & 15;
    const int g = lane >> 4;

    const int tile = blockIdx.x * WPB + wid;
    const int b0 = tile * TILE;
    const int bm = b0 + i15;

    // (1) index loads — first in issue order
    const int iw = w[bm];
    const int ic = c[bm];
    int ing[NNEG];
#pragma unroll
    for (int j = 0; j < NNEG; ++j) ing[j] = neg[bm * NNEG + j];

    // (2) comm_w fragments straight from global (16 KB -> L1-resident)
    bf16x8 bfr[4][4];
#pragma unroll
    for (int ks = 0; ks < 4; ++ks)
#pragma unroll
        for (int nb = 0; nb < 4; ++nb)
            bfr[ks][nb] = *(const bf16x8*)&cwb[(nb * 16 + i15) * D + ks * 32 + g * 8];

    // (3) node row gathers (needed first, for Q/P GEMM)
    const short* wp = nodeb + (size_t)iw * D + g * 8;
    const short* cp = nodeb + (size_t)ic * D + g * 8;
    FragU wf[4], cf[4];
#pragma unroll
    for (int ks = 0; ks < 4; ++ks) {
        wf[ks].v = *(const bf16x8*)(wp + ks * 32);
        cf[ks].v = *(const bf16x8*)(cp + ks * 32);
    }

    // (4) projection-row gathers: ONE 16B load per row per lane (64B/row total = 1 segment/pair)
    uint4 pv[1 + NNEG];
    pv[0] = *(const uint4*)(preb + (size_t)ic * 64 + g * 16);
#pragma unroll
    for (int j = 0; j < NNEG; ++j)
        pv[j + 1] = *(const uint4*)(preb + (size_t)ing[j] * 64 + g * 16);

    // (5) Q/P GEMMs
    const f32x4 z4 = {0.f, 0.f, 0.f, 0.f};
    f32x4 Qa[4] = {z4, z4, z4, z4};
    f32x4 Pa[4] = {z4, z4, z4, z4};
#pragma unroll
    for (int ks = 0; ks < 4; ++ks) {
        FragU pf;
#pragma unroll
        for (int t = 0; t < 4; ++t) {
            float al = __uint_as_float(wf[ks].u[t] << 16);
            float ah = __uint_as_float(wf[ks].u[t] & 0xffff0000u);
            float bl = __uint_as_float(cf[ks].u[t] << 16);
            float bh = __uint_as_float(cf[ks].u[t] & 0xffff0000u);
            pf.u[t] = pkbf(al * bl, ah * bh);
        }
#pragma unroll
        for (int nb = 0; nb < 4; ++nb) {
            Pa[nb] = __builtin_amdgcn_mfma_f32_16x16x32_bf16(wf[ks].v, bfr[ks][nb], Pa[nb], 0, 0, 0);
            Qa[nb] = __builtin_amdgcn_mfma_f32_16x16x32_bf16(pf.v, bfr[ks][nb], Qa[nb], 0, 0, 0);
        }
    }

    // (6) transpose q into bf16 B-frag layout via wave-private LDS
    //     write: q[pair=4g+r][col=16nb+i15];  read: q[pair=i15][k=g*8+e] (+32)
#pragma unroll
    for (int nb = 0; nb < 4; ++nb)
#pragma unroll
        for (int r = 0; r < 4; ++r)
            qt[wid][4 * g + r][nb * 16 + i15] = Qa[nb][r];
    asm volatile("s_waitcnt lgkmcnt(0)" ::: "memory");
    FragU q0, q1;
    {
        const float* rowp = &qt[wid][i15][0];
        float4 a = *(const float4*)(rowp + g * 8);
        float4 b = *(const float4*)(rowp + g * 8 + 4);
        q0.u[0] = pkbf(a.x, a.y); q0.u[1] = pkbf(a.z, a.w);
        q0.u[2] = pkbf(b.x, b.y); q0.u[3] = pkbf(b.z, b.w);
        float4 e = *(const float4*)(rowp + 32 + g * 8);
        float4 h = *(const float4*)(rowp + 32 + g * 8 + 4);
        q1.u[0] = pkbf(e.x, e.y); q1.u[1] = pkbf(e.z, e.w);
        q1.u[2] = pkbf(h.x, h.y); q1.u[3] = pkbf(h.z, h.w);
    }
    asm volatile("s_waitcnt lgkmcnt(0)" ::: "memory");

    // (7) loss dots: decode fp8 rows -> bf16 A-frags, C = pre_rows · q^T, take the diagonal
    const int rstar = i15 - 4 * g;
    const bool valid = ((unsigned)rstar) < 4u;
    float lossAcc = 0.f;
#pragma unroll
    for (int j = 0; j < 1 + NNEG; ++j) {
        FragU a0, a1;
        a0.u[0] = fp8pair_bf16(pv[j].x);
        a0.u[1] = fp8pair_bf16(pv[j].x >> 16);
        a0.u[2] = fp8pair_bf16(pv[j].y);
        a0.u[3] = fp8pair_bf16(pv[j].y >> 16);
        a1.u[0] = fp8pair_bf16(pv[j].z);
        a1.u[1] = fp8pair_bf16(pv[j].z >> 16);
        a1.u[2] = fp8pair_bf16(pv[j].w);
        a1.u[3] = fp8pair_bf16(pv[j].w >> 16);
        f32x4 Sa = z4;
        Sa = __builtin_amdgcn_mfma_f32_16x16x32_bf16(a0.v, q0.v, Sa, 0, 0, 0);
        Sa = __builtin_amdgcn_mfma_f32_16x16x32_bf16(a1.v, q1.v, Sa, 0, 0, 0);
        float s = (rstar == 0) ? Sa[0] : (rstar == 1) ? Sa[1] : (rstar == 2) ? Sa[2] : Sa[3];
        lossAcc += valid ? log_sigmoid(j == 0 ? s : -s) : 0.f;
    }

    // (8) epilogue: softmax(q), prior — through LDS, then 64-lane-contiguous dword stores
    //     (write segments 512 -> ~160 per wave; dword stores dodge the out+1 misalignment)
    float* __restrict__ outq = out + 1;
    float* __restrict__ outp = out + 1 + (size_t)B_TOTAL * K;
    float (*sq)[68] = (float(*)[68])qt[wid];

    // ---- Q softmax -> LDS -> coalesced stores ----
#pragma unroll
    for (int r = 0; r < 4; ++r) {
        float m = fmaxf(fmaxf(Qa[0][r], Qa[1][r]), fmaxf(Qa[2][r], Qa[3][r]));
        m = fmaxf(m, __shfl_xor(m, 1, 64)); m = fmaxf(m, __shfl_xor(m, 2, 64));
        m = fmaxf(m, __shfl_xor(m, 4, 64)); m = fmaxf(m, __shfl_xor(m, 8, 64));
        float e0 = __expf(Qa[0][r] - m), e1 = __expf(Qa[1][r] - m);
        float e2 = __expf(Qa[2][r] - m), e3 = __expf(Qa[3][r] - m);
        float s = e0 + e1 + e2 + e3;
        s += __shfl_xor(s, 1, 64); s += __shfl_xor(s, 2, 64);
        s += __shfl_xor(s, 4, 64); s += __shfl_xor(s, 8, 64);
        float inv = 1.f / s;
        sq[4 * g + r][i15]      = e0 * inv;
        sq[4 * g + r][16 + i15] = e1 * inv;
        sq[4 * g + r][32 + i15] = e2 * inv;
        sq[4 * g + r][48 + i15] = e3 * inv;
    }
    asm volatile("s_waitcnt lgkmcnt(0)" ::: "memory");
    {
        float* gbase = outq + (size_t)b0 * K;
#pragma unroll
        for (int i = 0; i < 16; ++i)
            gbase[i * 64 + lane] = sq[i][lane];
    }
    asm volatile("s_waitcnt lgkmcnt(0)" ::: "memory");

    // ---- P (prior) softmax -> LDS -> coalesced stores ----
#pragma unroll
    for (int r = 0; r < 4; ++r) {
        float m = fmaxf(fmaxf(Pa[0][r], Pa[1][r]), fmaxf(Pa[2][r], Pa[3][r]));
        m = fmaxf(m, __shfl_xor(m, 1, 64)); m = fmaxf(m, __shfl_xor(m, 2, 64));
        m = fmaxf(m, __shfl_xor(m, 4, 64)); m = fmaxf(m, __shfl_xor(m, 8, 64));
        float e0 = __expf(Pa[0][r] - m), e1 = __expf(Pa[1][r] - m);
        float e2 = __expf(Pa[2][r] - m), e3 = __expf(Pa[3][r] - m);
        float s = e0 + e1 + e2 + e3;
        s += __shfl_xor(s, 1, 64); s += __shfl_xor(s, 2, 64);
        s += __shfl_xor(s, 4, 64); s += __shfl_xor(s, 8, 64);
        float inv = 1.f / s;
        sq[4 * g + r][i15]      = e0 * inv;
        sq[4 * g + r][16 + i15] = e1 * inv;
        sq[4 * g + r][32 + i15] = e2 * inv;
        sq[4 * g + r][48 + i15] = e3 * inv;
    }
    asm volatile("s_waitcnt lgkmcnt(0)" ::: "memory");
    {
        float* gbase = outp + (size_t)b0 * K;
#pragma unroll
        for (int i = 0; i < 16; ++i)
            gbase[i * 64 + lane] = sq[i][lane];
    }

    // each pair counted exactly once per j
    float tot = lossAcc;
#pragma unroll
    for (int msk = 1; msk < 64; msk <<= 1) tot += __shfl_xor(tot, msk, 64);
    if (lane == 0) atomicAdd(out, -tot / (float)B_TOTAL);
}

// ---------------- fp32 fallback (R2 kernel, proven) ----------------
__global__ __launch_bounds__(BLOCK) void gcn_mfma_kernel(
    const int* __restrict__ w, const int* __restrict__ c, const int* __restrict__ neg,
    const float* __restrict__ node_emb, const float* __restrict__ ctx_emb,
    const float* __restrict__ comm_w, float* __restrict__ out)
{
    __shared__ __align__(16) short cw_lds[K * CWS];
    const int tid = threadIdx.x;
    const int lane = tid & 63;
    const int wid = tid >> 6;
    const int i15 = lane & 15;
    const int g = lane >> 4;

    for (int i = tid * 4; i < K * D; i += BLOCK * 4) {
        float4 v = *(const float4*)(comm_w + i);
        int row = i >> 7, col = i & 127;
        unsigned* dst = (unsigned*)&cw_lds[row * CWS + col];
        dst[0] = pkbf(v.x, v.y);
        dst[1] = pkbf(v.z, v.w);
    }
    __syncthreads();

    bf16x8 bfr[4][4];
#pragma unroll
    for (int ks = 0; ks < 4; ++ks)
#pragma unroll
        for (int nb = 0; nb < 4; ++nb)
            bfr[ks][nb] = *(const bf16x8*)&cw_lds[(nb * 16 + i15) * CWS + ks * 32 + g * 8];

    const int tile = blockIdx.x * WPB + wid;
    const int b0 = tile * TILE;
    const int bm = b0 + i15;
    const int iw = w[bm], ic = c[bm];
    int ing[NNEG];
#pragma unroll
    for (int j = 0; j < NNEG; ++j) ing[j] = neg[bm * NNEG + j];

    const f32x4 z4 = {0.f, 0.f, 0.f, 0.f};
    f32x4 Qa[4] = {z4, z4, z4, z4};
    f32x4 Pa[4] = {z4, z4, z4, z4};

#pragma unroll
    for (int ks = 0; ks < 4; ++ks) {
        const float* wp = node_emb + (size_t)iw * D + ks * 32 + g * 8;
        const float* cp = node_emb + (size_t)ic * D + ks * 32 + g * 8;
        float4 w0 = *(const float4*)wp, w1 = *(const float4*)(wp + 4);
        float4 c0 = *(const float4*)cp, c1 = *(const float4*)(cp + 4);
        FragU wf, pf;
        wf.u[0] = pkbf(w0.x, w0.y);               wf.u[1] = pkbf(w0.z, w0.w);
        wf.u[2] = pkbf(w1.x, w1.y);               wf.u[3] = pkbf(w1.z, w1.w);
        pf.u[0] = pkbf(w0.x * c0.x, w0.y * c0.y); pf.u[1] = pkbf(w0.z * c0.z, w0.w * c0.w);
        pf.u[2] = pkbf(w1.x * c1.x, w1.y * c1.y); pf.u[3] = pkbf(w1.z * c1.z, w1.w * c1.w);
#pragma unroll
        for (int nb = 0; nb < 4; ++nb) {
            Pa[nb] = __builtin_amdgcn_mfma_f32_16x16x32_bf16(wf.v, bfr[ks][nb], Pa[nb], 0, 0, 0);
            Qa[nb] = __builtin_amdgcn_mfma_f32_16x16x32_bf16(pf.v, bfr[ks][nb], Qa[nb], 0, 0, 0);
        }
    }

    float lossAcc = 0.f;
#pragma unroll
    for (int j = 0; j < 1 + NNEG; ++j) {
        const int idx = (j == 0) ? ic : ing[j - 1];
        const float* ebase = ctx_emb + (size_t)idx * D;
        f32x4 Fa[4] = {z4, z4, z4, z4};
#pragma unroll
        for (int ks = 0; ks < 4; ++ks) {
            const float* ep = ebase + ks * 32 + g * 8;
            float4 e0 = *(const float4*)ep, e1 = *(const float4*)(ep + 4);
            FragU ef;
            ef.u[0] = pkbf(e0.x, e0.y); ef.u[1] = pkbf(e0.z, e0.w);
            ef.u[2] = pkbf(e1.x, e1.y); ef.u[3] = pkbf(e1.z, e1.w);
#pragma unroll
            for (int nb = 0; nb < 4; ++nb)
                Fa[nb] = __builtin_amdgcn_mfma_f32_16x16x32_bf16(ef.v, bfr[ks][nb], Fa[nb], 0, 0, 0);
        }
#pragma unroll
        for (int r = 0; r < 4; ++r) {
            float s = Fa[0][r] * Qa[0][r] + Fa[1][r] * Qa[1][r] + Fa[2][r] * Qa[2][r] + Fa[3][r] * Qa[3][r];
            s += __shfl_xor(s, 1, 64);
            s += __shfl_xor(s, 2, 64);
            s += __shfl_xor(s, 4, 64);
            s += __shfl_xor(s, 8, 64);
            lossAcc += log_sigmoid(j == 0 ? s : -s);
        }
    }

    float* __restrict__ outq = out + 1;
    float* __restrict__ outp = out + 1 + (size_t)B_TOTAL * K;
#pragma unroll
    for (int r = 0; r < 4; ++r) {
        const size_t obase = (size_t)(b0 + g * 4 + r) * K + i15;
        {
            float m = fmaxf(fmaxf(Qa[0][r], Qa[1][r]), fmaxf(Qa[2][r], Qa[3][r]));
            m = fmaxf(m, __shfl_xor(m, 1, 64)); m = fmaxf(m, __shfl_xor(m, 2, 64));
            m = fmaxf(m, __shfl_xor(m, 4, 64)); m = fmaxf(m, __shfl_xor(m, 8, 64));
            float e0 = __expf(Qa[0][r] - m), e1 = __expf(Qa[1][r] - m);
            float e2 = __expf(Qa[2][r] - m), e3 = __expf(Qa[3][r] - m);
            float s = e0 + e1 + e2 + e3;
            s += __shfl_xor(s, 1, 64); s += __shfl_xor(s, 2, 64);
            s += __shfl_xor(s, 4, 64); s += __shfl_xor(s, 8, 64);
            float inv = 1.f / s;
            outq[obase]      = e0 * inv; outq[obase + 16] = e1 * inv;
            outq[obase + 32] = e2 * inv; outq[obase + 48] = e3 * inv;
        }
        {
            float m = fmaxf(fmaxf(Pa[0][r], Pa[1][r]), fmaxf(Pa[2][r], Pa[3][r]));
            m = fmaxf(m, __shfl_xor(m, 1, 64)); m = fmaxf(m, __shfl_xor(m, 2, 64));
            m = fmaxf(m, __shfl_xor(m, 4, 64)); m = fmaxf(m, __shfl_xor(m, 8, 64));
            float e0 = __expf(Pa[0][r] - m), e1 = __expf(Pa[1][r] - m);
            float e2 = __expf(Pa[2][r] - m), e3 = __expf(Pa[3][r] - m);
            float s = e0 + e1 + e2 + e3;
            s += __shfl_xor(s, 1, 64); s += __shfl_xor(s, 2, 64);
            s += __shfl_xor(s, 4, 64); s += __shfl_xor(s, 8, 64);
            float inv = 1.f / s;
            outp[obase]      = e0 * inv; outp[obase + 16] = e1 * inv;
            outp[obase + 32] = e2 * inv; outp[obase + 48] = e3 * inv;
        }
    }

    float tot = lossAcc;
#pragma unroll
    for (int msk = 1; msk < 64; msk <<= 1) tot += __shfl_xor(tot, msk, 64);
    if (lane == 0) atomicAdd(out, -tot / (16.f * (float)B_TOTAL));
}

extern "C" void kernel_launch(void* const* d_in, const int* in_sizes, int n_in,
                              void* d_out, int out_size, void* d_ws, size_t ws_size,
                              hipStream_t stream) {
    const int* w = (const int*)d_in[0];
    const int* c = (const int*)d_in[1];
    const int* neg = (const int*)d_in[2];
    // d_in[3] = temp (unused)
    const float* node_emb = (const float*)d_in[4];
    const float* ctx_emb = (const float*)d_in[5];
    const float* comm_w = (const float*)d_in[6];
    float* out = (float*)d_out;

    const size_t tbl_elems = (size_t)SIZE_N * D;           // 12.8M bf16
    const size_t pre_bytes = (size_t)SIZE_N * K;           // 6.4 MB fp8
    const size_t need = tbl_elems * sizeof(short) + pre_bytes + (size_t)K * D * sizeof(short); // ~32 MB

    if (ws_size >= need) {
        short* nodeb = (short*)d_ws;
        unsigned char* preb8 = (unsigned char*)(nodeb + tbl_elems);
        short* cwb = (short*)(preb8 + pre_bytes);
        prep_pass<<<CONV_BLOCKS + GEMM_BLOCKS, BLOCK, 0, stream>>>(
            node_emb, ctx_emb, comm_w, nodeb, cwb, preb8, out);
        gcn_mfma_bf16<<<GRID, BLOCK, 0, stream>>>(w, c, neg, nodeb, preb8, cwb, out);
    } else {
        zero_loss<<<1, 64, 0, stream>>>(out);
        gcn_mfma_kernel<<<GRID, BLOCK, 0, stream>>>(w, c, neg, node_emb, ctx_emb, comm_w, out);
    }
}

// Round 8
// 221.463 us; speedup vs baseline: 1.3188x; 1.3087x over previous
//
#include <hip/hip_runtime.h>
#include <math.h>

#define SIZE_N 100000
#define B_TOTAL 131072
#define D 128
#define K 64
#define NNEG 5
#define TILE 16
#define BLOCK 256
#define WPB 4
#define NTILES (B_TOTAL / TILE)        // 8192
#define GRID (NTILES / WPB)            // 2048
#define CWS 136                        // fallback LDS stride

#define CONV_BLOCKS 6250               // SIZE_N*D / 8 / BLOCK
#define GEMM_TILES 6250                // SIZE_N / 16
#define GEMM_BLOCKS ((GEMM_TILES + WPB - 1) / WPB)   // 1563

typedef short bf16x8 __attribute__((ext_vector_type(8)));
typedef float f32x4 __attribute__((ext_vector_type(4)));

union FragU { unsigned u[4]; bf16x8 v; };

// round-to-nearest-even fp32 -> bf16 (upper 16 bits)
__device__ __forceinline__ unsigned rne_hi(float x) {
    unsigned u = __float_as_uint(x);
    return (u + 0x7fffu + ((u >> 16) & 1u)) & 0xffff0000u;
}
__device__ __forceinline__ unsigned pkbf(float lo, float hi) {
    return (rne_hi(lo) >> 16) | rne_hi(hi);
}

__device__ __forceinline__ float log_sigmoid(float x) {
    return fminf(x, 0.f) - __logf(1.f + __expf(-fabsf(x)));
}

__global__ void zero_loss(float* out) { if (threadIdx.x == 0) out[0] = 0.f; }

// final reduce: 2048 per-block partials -> out[0] (no atomics anywhere)
__global__ __launch_bounds__(256) void finish_loss(const float* __restrict__ partials,
                                                   float* __restrict__ out) {
    float s = 0.f;
    for (int i = threadIdx.x; i < GRID; i += 256) s += partials[i];
#pragma unroll
    for (int msk = 1; msk < 64; msk <<= 1) s += __shfl_xor(s, msk, 64);
    __shared__ float ws[4];
    if ((threadIdx.x & 63) == 0) ws[threadIdx.x >> 6] = s;
    __syncthreads();
    if (threadIdx.x == 0) out[0] = -(ws[0] + ws[1] + ws[2] + ws[3]) / (float)B_TOTAL;
}

// ---------------- fused pre-pass ----------------
// blocks [0, GEMM_BLOCKS): pre = ctx_emb @ comm_w.T -> bf16 [SIZE_N][K]  (launched first: longer tail)
// blocks [GEMM_BLOCKS, GEMM_BLOCKS+CONV_BLOCKS): node_emb fp32->bf16 (+ comm_w convert + loss zero)
__global__ __launch_bounds__(BLOCK) void prep_pass(
    const float* __restrict__ node, const float* __restrict__ ctx,
    const float* __restrict__ cw,
    short* __restrict__ nodeb, short* __restrict__ cwb, short* __restrict__ preb,
    float* __restrict__ out)
{
    __shared__ __align__(16) short ps[WPB][16][72];
    const int tid = threadIdx.x;

    if (blockIdx.x >= GEMM_BLOCKS) {
        const int cb = blockIdx.x - GEMM_BLOCKS;
        const size_t i = ((size_t)cb * BLOCK + tid) * 8;
        float4 v0 = *(const float4*)(node + i), v1 = *(const float4*)(node + i + 4);
        FragU f;
        f.u[0] = pkbf(v0.x, v0.y); f.u[1] = pkbf(v0.z, v0.w);
        f.u[2] = pkbf(v1.x, v1.y); f.u[3] = pkbf(v1.z, v1.w);
        *(bf16x8*)(nodeb + i) = f.v;
        if (cb == 0) {
            if (tid == 0) out[0] = 0.f;
#pragma unroll
            for (int t = 0; t < 4; ++t) {
                const int j = (tid * 4 + t) * 8;   // covers K*D = 8192
                float4 a = *(const float4*)(cw + j), b = *(const float4*)(cw + j + 4);
                FragU fc;
                fc.u[0] = pkbf(a.x, a.y); fc.u[1] = pkbf(a.z, a.w);
                fc.u[2] = pkbf(b.x, b.y); fc.u[3] = pkbf(b.z, b.w);
                *(bf16x8*)(cwb + j) = fc.v;
            }
        }
        return;
    }

    // ---- ctx @ comm_w.T GEMM branch (reads f32 inputs directly) ----
    const int lane = tid & 63, wid = tid >> 6;
    const int i15 = lane & 15, g = lane >> 4;
    const int tile = blockIdx.x * WPB + wid;
    if (tile >= GEMM_TILES) return;

    bf16x8 bfr[4][4];
#pragma unroll
    for (int ks = 0; ks < 4; ++ks)
#pragma unroll
        for (int nb = 0; nb < 4; ++nb) {
            const float* p = cw + (nb * 16 + i15) * D + ks * 32 + g * 8;
            float4 a = *(const float4*)p, b = *(const float4*)(p + 4);
            FragU f;
            f.u[0] = pkbf(a.x, a.y); f.u[1] = pkbf(a.z, a.w);
            f.u[2] = pkbf(b.x, b.y); f.u[3] = pkbf(b.z, b.w);
            bfr[ks][nb] = f.v;
        }

    const float* rp = ctx + (size_t)(tile * 16 + i15) * D + g * 8;
    const f32x4 z4 = {0.f, 0.f, 0.f, 0.f};
    f32x4 Ca[4] = {z4, z4, z4, z4};
#pragma unroll
    for (int ks = 0; ks < 4; ++ks) {
        float4 a = *(const float4*)(rp + ks * 32), b = *(const float4*)(rp + ks * 32 + 4);
        FragU f;
        f.u[0] = pkbf(a.x, a.y); f.u[1] = pkbf(a.z, a.w);
        f.u[2] = pkbf(b.x, b.y); f.u[3] = pkbf(b.z, b.w);
#pragma unroll
        for (int nb = 0; nb < 4; ++nb)
            Ca[nb] = __builtin_amdgcn_mfma_f32_16x16x32_bf16(f.v, bfr[ks][nb], Ca[nb], 0, 0, 0);
    }
    // LDS repack -> 16B-aligned full-line stores
#pragma unroll
    for (int nb = 0; nb < 4; ++nb)
#pragma unroll
        for (int r = 0; r < 4; ++r)
            ps[wid][4 * g + r][nb * 16 + i15] = (short)(rne_hi(Ca[nb][r]) >> 16);
    asm volatile("s_waitcnt lgkmcnt(0)" ::: "memory");
    {
        const int ro = lane >> 2, co = (lane & 3) * 16;
        bf16x8 v0 = *(const bf16x8*)&ps[wid][ro][co];
        bf16x8 v1 = *(const bf16x8*)&ps[wid][ro][co + 8];
        short* dst = preb + (size_t)(tile * 16 + ro) * K + co;   // 16B-aligned (preb offset % 16 == 0)
        *(bf16x8*)dst = v0;
        *(bf16x8*)(dst + 8) = v1;
    }
}

// ---------------- main kernel: Q/P GEMM + precomputed-projection loss dots ----------------
// Loss path: wave reduce -> block LDS reduce -> ONE plain store to partials[blockIdx.x].
// (R6 theory test, correctly wired this time: replaces 8192 same-address atomicAdds.)
__global__ __launch_bounds__(BLOCK, 2) void gcn_mfma_bf16(
    const int* __restrict__ w, const int* __restrict__ c, const int* __restrict__ neg,
    const short* __restrict__ nodeb, const short* __restrict__ preb,
    const short* __restrict__ cwb, float* __restrict__ out, float* __restrict__ partials)
{
    __shared__ __align__(16) float qt[WPB][16][68];   // wave-private q transpose buffer
    __shared__ float lsum[WPB];

    const int tid = threadIdx.x;
    const int lane = tid & 63;
    const int wid = tid >> 6;
    const int i15 = lane & 15;
    const int g = lane >> 4;

    const int tile = blockIdx.x * WPB + wid;
    const int b0 = tile * TILE;
    const int bm = b0 + i15;

    // (1) index loads — first in issue order
    const int iw = w[bm];
    const int ic = c[bm];
    int ing[NNEG];
#pragma unroll
    for (int j = 0; j < NNEG; ++j) ing[j] = neg[bm * NNEG + j];

    // (2) comm_w fragments straight from global (16 KB -> L1-resident)
    bf16x8 bfr[4][4];
#pragma unroll
    for (int ks = 0; ks < 4; ++ks)
#pragma unroll
        for (int nb = 0; nb < 4; ++nb)
            bfr[ks][nb] = *(const bf16x8*)&cwb[(nb * 16 + i15) * D + ks * 32 + g * 8];

    // (3) node row gathers (needed first, for Q/P GEMM)
    const short* wp = nodeb + (size_t)iw * D + g * 8;
    const short* cp = nodeb + (size_t)ic * D + g * 8;
    FragU wf[4], cf[4];
#pragma unroll
    for (int ks = 0; ks < 4; ++ks) {
        wf[ks].v = *(const bf16x8*)(wp + ks * 32);
        cf[ks].v = *(const bf16x8*)(cp + ks * 32);
    }

    // (4) ALL projection-row gathers issue upfront (128 B/row, A-frag layout: row=i15, k=g*8+e)
    bf16x8 pr0[1 + NNEG], pr1[1 + NNEG];
    {
        const short* p = preb + (size_t)ic * K + g * 8;
        pr0[0] = *(const bf16x8*)p;
        pr1[0] = *(const bf16x8*)(p + 32);
    }
#pragma unroll
    for (int j = 0; j < NNEG; ++j) {
        const short* p = preb + (size_t)ing[j] * K + g * 8;
        pr0[j + 1] = *(const bf16x8*)p;
        pr1[j + 1] = *(const bf16x8*)(p + 32);
    }

    // (5) Q/P GEMMs
    const f32x4 z4 = {0.f, 0.f, 0.f, 0.f};
    f32x4 Qa[4] = {z4, z4, z4, z4};
    f32x4 Pa[4] = {z4, z4, z4, z4};
#pragma unroll
    for (int ks = 0; ks < 4; ++ks) {
        FragU pf;
#pragma unroll
        for (int t = 0; t < 4; ++t) {
            float al = __uint_as_float(wf[ks].u[t] << 16);
            float ah = __uint_as_float(wf[ks].u[t] & 0xffff0000u);
            float bl = __uint_as_float(cf[ks].u[t] << 16);
            float bh = __uint_as_float(cf[ks].u[t] & 0xffff0000u);
            pf.u[t] = pkbf(al * bl, ah * bh);
        }
#pragma unroll
        for (int nb = 0; nb < 4; ++nb) {
            Pa[nb] = __builtin_amdgcn_mfma_f32_16x16x32_bf16(wf[ks].v, bfr[ks][nb], Pa[nb], 0, 0, 0);
            Qa[nb] = __builtin_amdgcn_mfma_f32_16x16x32_bf16(pf.v, bfr[ks][nb], Qa[nb], 0, 0, 0);
        }
    }

    // (6) transpose q into bf16 B-frag layout via wave-private LDS
    //     write: q[pair=4g+r][col=16nb+i15];  read: q[pair=i15][k=g*8+e] (+32)
#pragma unroll
    for (int nb = 0; nb < 4; ++nb)
#pragma unroll
        for (int r = 0; r < 4; ++r)
            qt[wid][4 * g + r][nb * 16 + i15] = Qa[nb][r];
    asm volatile("s_waitcnt lgkmcnt(0)" ::: "memory");
    FragU q0, q1;
    {
        const float* rowp = &qt[wid][i15][0];
        float4 a = *(const float4*)(rowp + g * 8);
        float4 b = *(const float4*)(rowp + g * 8 + 4);
        q0.u[0] = pkbf(a.x, a.y); q0.u[1] = pkbf(a.z, a.w);
        q0.u[2] = pkbf(b.x, b.y); q0.u[3] = pkbf(b.z, b.w);
        float4 e = *(const float4*)(rowp + 32 + g * 8);
        float4 h = *(const float4*)(rowp + 32 + g * 8 + 4);
        q1.u[0] = pkbf(e.x, e.y); q1.u[1] = pkbf(e.z, e.w);
        q1.u[2] = pkbf(h.x, h.y); q1.u[3] = pkbf(h.z, h.w);
    }

    // (7) loss dots: C = pre_rows · q^T, take the diagonal (pair i15 lives at lane g=i15>>2)
    const int rstar = i15 - 4 * g;
    const bool valid = ((unsigned)rstar) < 4u;
    float lossAcc = 0.f;
#pragma unroll
    for (int j = 0; j < 1 + NNEG; ++j) {
        f32x4 Sa = z4;
        Sa = __builtin_amdgcn_mfma_f32_16x16x32_bf16(pr0[j], q0.v, Sa, 0, 0, 0);
        Sa = __builtin_amdgcn_mfma_f32_16x16x32_bf16(pr1[j], q1.v, Sa, 0, 0, 0);
        float s = (rstar == 0) ? Sa[0] : (rstar == 1) ? Sa[1] : (rstar == 2) ? Sa[2] : Sa[3];
        lossAcc += valid ? log_sigmoid(j == 0 ? s : -s) : 0.f;
    }

    // (8) epilogue: softmax(q), prior — R4-proven addressing, cached stores, into d_out
    float* __restrict__ outq = out + 1;
    float* __restrict__ outp = out + 1 + (size_t)B_TOTAL * K;
#pragma unroll
    for (int r = 0; r < 4; ++r) {
        const size_t obase = (size_t)(b0 + g * 4 + r) * K + i15;
        {
            float m = fmaxf(fmaxf(Qa[0][r], Qa[1][r]), fmaxf(Qa[2][r], Qa[3][r]));
            m = fmaxf(m, __shfl_xor(m, 1, 64)); m = fmaxf(m, __shfl_xor(m, 2, 64));
            m = fmaxf(m, __shfl_xor(m, 4, 64)); m = fmaxf(m, __shfl_xor(m, 8, 64));
            float e0 = __expf(Qa[0][r] - m), e1 = __expf(Qa[1][r] - m);
            float e2 = __expf(Qa[2][r] - m), e3 = __expf(Qa[3][r] - m);
            float s = e0 + e1 + e2 + e3;
            s += __shfl_xor(s, 1, 64); s += __shfl_xor(s, 2, 64);
            s += __shfl_xor(s, 4, 64); s += __shfl_xor(s, 8, 64);
            float inv = 1.f / s;
            outq[obase]      = e0 * inv;
            outq[obase + 16] = e1 * inv;
            outq[obase + 32] = e2 * inv;
            outq[obase + 48] = e3 * inv;
        }
        {
            float m = fmaxf(fmaxf(Pa[0][r], Pa[1][r]), fmaxf(Pa[2][r], Pa[3][r]));
            m = fmaxf(m, __shfl_xor(m, 1, 64)); m = fmaxf(m, __shfl_xor(m, 2, 64));
            m = fmaxf(m, __shfl_xor(m, 4, 64)); m = fmaxf(m, __shfl_xor(m, 8, 64));
            float e0 = __expf(Pa[0][r] - m), e1 = __expf(Pa[1][r] - m);
            float e2 = __expf(Pa[2][r] - m), e3 = __expf(Pa[3][r] - m);
            float s = e0 + e1 + e2 + e3;
            s += __shfl_xor(s, 1, 64); s += __shfl_xor(s, 2, 64);
            s += __shfl_xor(s, 4, 64); s += __shfl_xor(s, 8, 64);
            float inv = 1.f / s;
            outp[obase]      = e0 * inv;
            outp[obase + 16] = e1 * inv;
            outp[obase + 32] = e2 * inv;
            outp[obase + 48] = e3 * inv;
        }
    }

    // (9) loss partial: one plain store per block, no atomics
    float tot = lossAcc;
#pragma unroll
    for (int msk = 1; msk < 64; msk <<= 1) tot += __shfl_xor(tot, msk, 64);
    if (lane == 0) lsum[wid] = tot;
    __syncthreads();
    if (tid == 0) partials[blockIdx.x] = lsum[0] + lsum[1] + lsum[2] + lsum[3];
}

// ---------------- fp32 fallback (R2 kernel, proven) ----------------
__global__ __launch_bounds__(BLOCK) void gcn_mfma_kernel(
    const int* __restrict__ w, const int* __restrict__ c, const int* __restrict__ neg,
    const float* __restrict__ node_emb, const float* __restrict__ ctx_emb,
    const float* __restrict__ comm_w, float* __restrict__ out)
{
    __shared__ __align__(16) short cw_lds[K * CWS];
    const int tid = threadIdx.x;
    const int lane = tid & 63;
    const int wid = tid >> 6;
    const int i15 = lane & 15;
    const int g = lane >> 4;

    for (int i = tid * 4; i < K * D; i += BLOCK * 4) {
        float4 v = *(const float4*)(comm_w + i);
        int row = i >> 7, col = i & 127;
        unsigned* dst = (unsigned*)&cw_lds[row * CWS + col];
        dst[0] = pkbf(v.x, v.y);
        dst[1] = pkbf(v.z, v.w);
    }
    __syncthreads();

    bf16x8 bfr[4][4];
#pragma unroll
    for (int ks = 0; ks < 4; ++ks)
#pragma unroll
        for (int nb = 0; nb < 4; ++nb)
            bfr[ks][nb] = *(const bf16x8*)&cw_lds[(nb * 16 + i15) * CWS + ks * 32 + g * 8];

    const int tile = blockIdx.x * WPB + wid;
    const int b0 = tile * TILE;
    const int bm = b0 + i15;
    const int iw = w[bm], ic = c[bm];
    int ing[NNEG];
#pragma unroll
    for (int j = 0; j < NNEG; ++j) ing[j] = neg[bm * NNEG + j];

    const f32x4 z4 = {0.f, 0.f, 0.f, 0.f};
    f32x4 Qa[4] = {z4, z4, z4, z4};
    f32x4 Pa[4] = {z4, z4, z4, z4};

#pragma unroll
    for (int ks = 0; ks < 4; ++ks) {
        const float* wp = node_emb + (size_t)iw * D + ks * 32 + g * 8;
        const float* cp = node_emb + (size_t)ic * D + ks * 32 + g * 8;
        float4 w0 = *(const float4*)wp, w1 = *(const float4*)(wp + 4);
        float4 c0 = *(const float4*)cp, c1 = *(const float4*)(cp + 4);
        FragU wf, pf;
        wf.u[0] = pkbf(w0.x, w0.y);               wf.u[1] = pkbf(w0.z, w0.w);
        wf.u[2] = pkbf(w1.x, w1.y);               wf.u[3] = pkbf(w1.z, w1.w);
        pf.u[0] = pkbf(w0.x * c0.x, w0.y * c0.y); pf.u[1] = pkbf(w0.z * c0.z, w0.w * c0.w);
        pf.u[2] = pkbf(w1.x * c1.x, w1.y * c1.y); pf.u[3] = pkbf(w1.z * c1.z, w1.w * c1.w);
#pragma unroll
        for (int nb = 0; nb < 4; ++nb) {
            Pa[nb] = __builtin_amdgcn_mfma_f32_16x16x32_bf16(wf.v, bfr[ks][nb], Pa[nb], 0, 0, 0);
            Qa[nb] = __builtin_amdgcn_mfma_f32_16x16x32_bf16(pf.v, bfr[ks][nb], Qa[nb], 0, 0, 0);
        }
    }

    float lossAcc = 0.f;
#pragma unroll
    for (int j = 0; j < 1 + NNEG; ++j) {
        const int idx = (j == 0) ? ic : ing[j - 1];
        const float* ebase = ctx_emb + (size_t)idx * D;
        f32x4 Fa[4] = {z4, z4, z4, z4};
#pragma unroll
        for (int ks = 0; ks < 4; ++ks) {
            const float* ep = ebase + ks * 32 + g * 8;
            float4 e0 = *(const float4*)ep, e1 = *(const float4*)(ep + 4);
            FragU ef;
            ef.u[0] = pkbf(e0.x, e0.y); ef.u[1] = pkbf(e0.z, e0.w);
            ef.u[2] = pkbf(e1.x, e1.y); ef.u[3] = pkbf(e1.z, e1.w);
#pragma unroll
            for (int nb = 0; nb < 4; ++nb)
                Fa[nb] = __builtin_amdgcn_mfma_f32_16x16x32_bf16(ef.v, bfr[ks][nb], Fa[nb], 0, 0, 0);
        }
#pragma unroll
        for (int r = 0; r < 4; ++r) {
            float s = Fa[0][r] * Qa[0][r] + Fa[1][r] * Qa[1][r] + Fa[2][r] * Qa[2][r] + Fa[3][r] * Qa[3][r];
            s += __shfl_xor(s, 1, 64);
            s += __shfl_xor(s, 2, 64);
            s += __shfl_xor(s, 4, 64);
            s += __shfl_xor(s, 8, 64);
            lossAcc += log_sigmoid(j == 0 ? s : -s);
        }
    }

    float* __restrict__ outq = out + 1;
    float* __restrict__ outp = out + 1 + (size_t)B_TOTAL * K;
#pragma unroll
    for (int r = 0; r < 4; ++r) {
        const size_t obase = (size_t)(b0 + g * 4 + r) * K + i15;
        {
            float m = fmaxf(fmaxf(Qa[0][r], Qa[1][r]), fmaxf(Qa[2][r], Qa[3][r]));
            m = fmaxf(m, __shfl_xor(m, 1, 64)); m = fmaxf(m, __shfl_xor(m, 2, 64));
            m = fmaxf(m, __shfl_xor(m, 4, 64)); m = fmaxf(m, __shfl_xor(m, 8, 64));
            float e0 = __expf(Qa[0][r] - m), e1 = __expf(Qa[1][r] - m);
            float e2 = __expf(Qa[2][r] - m), e3 = __expf(Qa[3][r] - m);
            float s = e0 + e1 + e2 + e3;
            s += __shfl_xor(s, 1, 64); s += __shfl_xor(s, 2, 64);
            s += __shfl_xor(s, 4, 64); s += __shfl_xor(s, 8, 64);
            float inv = 1.f / s;
            outq[obase]      = e0 * inv; outq[obase + 16] = e1 * inv;
            outq[obase + 32] = e2 * inv; outq[obase + 48] = e3 * inv;
        }
        {
            float m = fmaxf(fmaxf(Pa[0][r], Pa[1][r]), fmaxf(Pa[2][r], Pa[3][r]));
            m = fmaxf(m, __shfl_xor(m, 1, 64)); m = fmaxf(m, __shfl_xor(m, 2, 64));
            m = fmaxf(m, __shfl_xor(m, 4, 64)); m = fmaxf(m, __shfl_xor(m, 8, 64));
            float e0 = __expf(Pa[0][r] - m), e1 = __expf(Pa[1][r] - m);
            float e2 = __expf(Pa[2][r] - m), e3 = __expf(Pa[3][r] - m);
            float s = e0 + e1 + e2 + e3;
            s += __shfl_xor(s, 1, 64); s += __shfl_xor(s, 2, 64);
            s += __shfl_xor(s, 4, 64); s += __shfl_xor(s, 8, 64);
            float inv = 1.f / s;
            outp[obase]      = e0 * inv; outp[obase + 16] = e1 * inv;
            outp[obase + 32] = e2 * inv; outp[obase + 48] = e3 * inv;
        }
    }

    float tot = lossAcc;
#pragma unroll
    for (int msk = 1; msk < 64; msk <<= 1) tot += __shfl_xor(tot, msk, 64);
    if (lane == 0) atomicAdd(out, -tot / (16.f * (float)B_TOTAL));
}

extern "C" void kernel_launch(void* const* d_in, const int* in_sizes, int n_in,
                              void* d_out, int out_size, void* d_ws, size_t ws_size,
                              hipStream_t stream) {
    const int* w = (const int*)d_in[0];
    const int* c = (const int*)d_in[1];
    const int* neg = (const int*)d_in[2];
    // d_in[3] = temp (unused)
    const float* node_emb = (const float*)d_in[4];
    const float* ctx_emb = (const float*)d_in[5];
    const float* comm_w = (const float*)d_in[6];
    float* out = (float*)d_out;

    const size_t tbl_elems = (size_t)SIZE_N * D;
    const size_t pre_elems = (size_t)SIZE_N * K;
    const size_t need = (tbl_elems + (size_t)K * D + pre_elems) * sizeof(short)
                        + (size_t)GRID * sizeof(float);                 // ~38.4 MB + 8 KB

    if (ws_size >= need) {
        short* nodeb = (short*)d_ws;
        short* cwb = nodeb + tbl_elems;
        short* preb = cwb + (size_t)K * D;
        float* partials = (float*)(preb + pre_elems);   // byte offset 38.4e6, divisible by 4
        prep_pass<<<CONV_BLOCKS + GEMM_BLOCKS, BLOCK, 0, stream>>>(
            node_emb, ctx_emb, comm_w, nodeb, cwb, preb, out);
        gcn_mfma_bf16<<<GRID, BLOCK, 0, stream>>>(w, c, neg, nodeb, preb, cwb, out, partials);
        finish_loss<<<1, 256, 0, stream>>>(partials, out);
    } else {
        zero_loss<<<1, 64, 0, stream>>>(out);
        gcn_mfma_kernel<<<GRID, BLOCK, 0, stream>>>(w, c, neg, node_emb, ctx_emb, comm_w, out);
    }
}